// Round 1
// baseline (2038.406 us; speedup 1.0000x reference)
//
#include <hip/hip_runtime.h>

#define NU 50000
#define NI 100000
#define NN 150000
#define NE 2400000
#define DD 64
#define NL 3
#define CHUNK 1024
#define NB ((NN + CHUNK - 1) / CHUNK)   // 147 scan blocks

// ---- init: ego = concat(user_emb, item_emb); out[:, 0:64] = ego (layer-0, un-normalized)
__global__ void init_kernel(const float* __restrict__ uemb, const float* __restrict__ iemb,
                            float* __restrict__ ego, float* __restrict__ out) {
    int i = blockIdx.x * blockDim.x + threadIdx.x;
    if (i >= NN * DD) return;
    int n = i >> 6, d = i & 63;
    float v = (n < NU) ? uemb[i] : iemb[i - NU * DD];
    ego[i] = v;
    out[n * (DD * (NL + 1)) + d] = v;
}

// ---- CSR build: histogram of dst
__global__ void hist_kernel(const int* __restrict__ dst, int* __restrict__ counts) {
    int e = blockIdx.x * blockDim.x + threadIdx.x;
    if (e < NE) atomicAdd(&counts[dst[e]], 1);
}

// ---- scan stage A: per-block (1024-elem chunk) totals
__global__ void scanA_kernel(const int* __restrict__ counts, int* __restrict__ bsum) {
    __shared__ int sh[256];
    int t = threadIdx.x, b = blockIdx.x;
    int base = b * CHUNK + t * 4;
    int s = 0;
#pragma unroll
    for (int i = 0; i < 4; ++i) { int idx = base + i; if (idx < NN) s += counts[idx]; }
    sh[t] = s; __syncthreads();
    for (int off = 128; off > 0; off >>= 1) {
        if (t < off) sh[t] += sh[t + off];
        __syncthreads();
    }
    if (t == 0) bsum[b] = sh[0];
}

// ---- scan stage B: exclusive scan of the NB(=147) block sums, one block
__global__ void scanB_kernel(int* __restrict__ bsum, int* __restrict__ offs) {
    __shared__ int sh[256];
    int t = threadIdx.x;
    int v = (t < NB) ? bsum[t] : 0;
    sh[t] = v; __syncthreads();
    for (int off = 1; off < 256; off <<= 1) {
        int add = (t >= off) ? sh[t - off] : 0;
        __syncthreads();
        sh[t] += add;
        __syncthreads();
    }
    if (t < NB) bsum[t] = sh[t] - v;          // exclusive block offset
    if (t == NB - 1) offs[NN] = sh[t];        // total == NE
}

// ---- scan stage C: full exclusive scan -> offs
__global__ void scanC_kernel(const int* __restrict__ counts, const int* __restrict__ bsum,
                             int* __restrict__ offs) {
    __shared__ int sh[256];
    int t = threadIdx.x, b = blockIdx.x;
    int base = b * CHUNK + t * 4;
    int c[4]; int tsum = 0;
#pragma unroll
    for (int i = 0; i < 4; ++i) { int idx = base + i; c[i] = (idx < NN) ? counts[idx] : 0; tsum += c[i]; }
    sh[t] = tsum; __syncthreads();
    for (int off = 1; off < 256; off <<= 1) {
        int add = (t >= off) ? sh[t - off] : 0;
        __syncthreads();
        sh[t] += add;
        __syncthreads();
    }
    int excl = sh[t] - tsum + bsum[b];
#pragma unroll
    for (int i = 0; i < 4; ++i) {
        int idx = base + i;
        if (idx < NN) offs[idx] = excl;
        excl += c[i];
    }
}

// ---- CSR fill: (src, val) pairs bucketed by dst
__global__ void fill_kernel(const int* __restrict__ src, const int* __restrict__ dst,
                            const float* __restrict__ vals, const int* __restrict__ offs,
                            int* __restrict__ cursor, int2* __restrict__ pair) {
    int e = blockIdx.x * blockDim.x + threadIdx.x;
    if (e >= NE) return;
    int d = dst[e];
    int pos = offs[d] + atomicAdd(&cursor[d], 1);
    pair[pos] = make_int2(src[e], __float_as_int(vals[e]));
}

// ---- gather SpMM: one wave per node, lane = dim. No atomics.
__global__ void spmm_kernel(const int* __restrict__ offs, const int2* __restrict__ pair,
                            const float* __restrict__ ego, float* __restrict__ side) {
    int gid = blockIdx.x * blockDim.x + threadIdx.x;
    int node = gid >> 6, lane = gid & 63;
    if (node >= NN) return;
    int beg = offs[node], end = offs[node + 1];
    float acc = 0.f;
    for (int i = beg; i < end; ++i) {
        int2 p = pair[i];                       // same addr across wave -> broadcast
        acc = fmaf(__int_as_float(p.y), ego[p.x * DD + lane], acc);  // coalesced 256B gather
    }
    side[node * DD + lane] = acc;
}

// ---- fused projection + leaky_relu + sum + in-place ego update + l2norm output.
// One thread per node; side/ego rows live in VGPRs; W/b addresses are
// wave-uniform -> scalar loads (SGPR broadcast), so inner loop is pure v_fma.
__global__ __launch_bounds__(256) void update_kernel(
        const float* __restrict__ side, float* __restrict__ ego,
        const float* __restrict__ Wg, const float* __restrict__ bg,
        const float* __restrict__ Wb, const float* __restrict__ bb,
        float* __restrict__ out, int layer) {
    int n = blockIdx.x * blockDim.x + threadIdx.x;
    if (n >= NN) return;
    float s[DD], m[DD];
    const float4* sp = (const float4*)(side + n * DD);
    const float4* ep = (const float4*)(ego + n * DD);
#pragma unroll
    for (int k = 0; k < DD / 4; ++k) {
        float4 sv = sp[k], ev = ep[k];
        s[4 * k + 0] = sv.x; s[4 * k + 1] = sv.y; s[4 * k + 2] = sv.z; s[4 * k + 3] = sv.w;
        m[4 * k + 0] = sv.x * ev.x; m[4 * k + 1] = sv.y * ev.y;
        m[4 * k + 2] = sv.z * ev.z; m[4 * k + 3] = sv.w * ev.w;
    }
    float* erow = ego + n * DD;
    float nrm = 0.f;
    for (int jo = 0; jo < DD / 4; ++jo) {
        float vv[4];
#pragma unroll
        for (int ji = 0; ji < 4; ++ji) {
            int j = jo * 4 + ji;
            float ag = bg[j], ab = bb[j];
            const float* wgr = Wg + j * DD;
            const float* wbr = Wb + j * DD;
#pragma unroll
            for (int k = 0; k < DD; ++k) {
                ag = fmaf(s[k], wgr[k], ag);
                ab = fmaf(m[k], wbr[k], ab);
            }
            ag = (ag > 0.f) ? ag : 0.01f * ag;   // leaky_relu
            ab = (ab > 0.f) ? ab : 0.01f * ab;
            float v = ag + ab;
            vv[ji] = v;
            nrm = fmaf(v, v, nrm);
        }
        ((float4*)erow)[jo] = make_float4(vv[0], vv[1], vv[2], vv[3]);
    }
    float rinv = 1.f / fmaxf(sqrtf(nrm), 1e-12f);
    float4* orow = (float4*)(out + n * (DD * (NL + 1)) + (layer + 1) * DD);
    const float4* er4 = (const float4*)erow;
#pragma unroll
    for (int k = 0; k < DD / 4; ++k) {
        float4 v = er4[k];
        orow[k] = make_float4(v.x * rinv, v.y * rinv, v.z * rinv, v.w * rinv);
    }
}

extern "C" void kernel_launch(void* const* d_in, const int* in_sizes, int n_in,
                              void* d_out, int out_size, void* d_ws, size_t ws_size,
                              hipStream_t stream) {
    const int*   edge_src  = (const int*)d_in[0];
    const int*   edge_dst  = (const int*)d_in[1];
    const float* edge_vals = (const float*)d_in[2];
    const float* uemb      = (const float*)d_in[3];
    const float* iemb      = (const float*)d_in[4];
    const float* Wgc       = (const float*)d_in[5];
    const float* bgc       = (const float*)d_in[6];
    const float* Wbi       = (const float*)d_in[7];
    const float* bbi       = (const float*)d_in[8];
    float* out = (float*)d_out;

    // workspace carve (~97 MB): counts, offs, bsum, csr pairs, ego, side
    char* p = (char*)d_ws;
    auto alloc = [&](size_t bytes) { char* r = p; p += (bytes + 255) & ~(size_t)255; return r; };
    int*   counts = (int*)alloc((size_t)NN * 4);
    int*   offs   = (int*)alloc((size_t)(NN + 1) * 4);
    int*   bsum   = (int*)alloc((size_t)NB * 4);
    int2*  pair   = (int2*)alloc((size_t)NE * 8);
    float* ego    = (float*)alloc((size_t)NN * DD * 4);
    float* side   = (float*)alloc((size_t)NN * DD * 4);

    hipMemsetAsync(counts, 0, (size_t)NN * 4, stream);
    init_kernel<<<(NN * DD + 255) / 256, 256, 0, stream>>>(uemb, iemb, ego, out);
    hist_kernel<<<(NE + 255) / 256, 256, 0, stream>>>(edge_dst, counts);
    scanA_kernel<<<NB, 256, 0, stream>>>(counts, bsum);
    scanB_kernel<<<1, 256, 0, stream>>>(bsum, offs);
    scanC_kernel<<<NB, 256, 0, stream>>>(counts, bsum, offs);
    hipMemsetAsync(counts, 0, (size_t)NN * 4, stream);
    fill_kernel<<<(NE + 255) / 256, 256, 0, stream>>>(edge_src, edge_dst, edge_vals, offs, counts, pair);

    for (int l = 0; l < NL; ++l) {
        spmm_kernel<<<(NN * 64 + 255) / 256, 256, 0, stream>>>(offs, pair, ego, side);
        update_kernel<<<(NN + 255) / 256, 256, 0, stream>>>(
            side, ego, Wgc + l * DD * DD, bgc + l * DD, Wbi + l * DD * DD, bbi + l * DD,
            out, l);
    }
}

// Round 2
// 1505.703 us; speedup vs baseline: 1.3538x; 1.3538x over previous
//
#include <hip/hip_runtime.h>

#define NU 50000
#define NI 100000
#define NN 150000
#define NE 2400000
#define DD 64
#define NL 3
#define CHUNK 1024
#define NB ((NN + CHUNK - 1) / CHUNK)   // 147 scan blocks

// ---- init: ego = concat(user_emb, item_emb); out[:, 0:64] = ego (layer-0, un-normalized)
__global__ void init_kernel(const float* __restrict__ uemb, const float* __restrict__ iemb,
                            float* __restrict__ ego, float* __restrict__ out) {
    int i = blockIdx.x * blockDim.x + threadIdx.x;
    if (i >= NN * DD) return;
    int n = i >> 6, d = i & 63;
    float v = (n < NU) ? uemb[i] : iemb[i - NU * DD];
    ego[i] = v;
    out[n * (DD * (NL + 1)) + d] = v;
}

// ---- CSR build: histogram of dst
__global__ void hist_kernel(const int* __restrict__ dst, int* __restrict__ counts) {
    int e = blockIdx.x * blockDim.x + threadIdx.x;
    if (e < NE) atomicAdd(&counts[dst[e]], 1);
}

// ---- scan stage A: per-block (1024-elem chunk) totals
__global__ void scanA_kernel(const int* __restrict__ counts, int* __restrict__ bsum) {
    __shared__ int sh[256];
    int t = threadIdx.x, b = blockIdx.x;
    int base = b * CHUNK + t * 4;
    int s = 0;
#pragma unroll
    for (int i = 0; i < 4; ++i) { int idx = base + i; if (idx < NN) s += counts[idx]; }
    sh[t] = s; __syncthreads();
    for (int off = 128; off > 0; off >>= 1) {
        if (t < off) sh[t] += sh[t + off];
        __syncthreads();
    }
    if (t == 0) bsum[b] = sh[0];
}

// ---- scan stage B: exclusive scan of the NB(=147) block sums, one block
__global__ void scanB_kernel(int* __restrict__ bsum, int* __restrict__ offs) {
    __shared__ int sh[256];
    int t = threadIdx.x;
    int v = (t < NB) ? bsum[t] : 0;
    sh[t] = v; __syncthreads();
    for (int off = 1; off < 256; off <<= 1) {
        int add = (t >= off) ? sh[t - off] : 0;
        __syncthreads();
        sh[t] += add;
        __syncthreads();
    }
    if (t < NB) bsum[t] = sh[t] - v;          // exclusive block offset
    if (t == NB - 1) offs[NN] = sh[t];        // total == NE
}

// ---- scan stage C: full exclusive scan -> offs
__global__ void scanC_kernel(const int* __restrict__ counts, const int* __restrict__ bsum,
                             int* __restrict__ offs) {
    __shared__ int sh[256];
    int t = threadIdx.x, b = blockIdx.x;
    int base = b * CHUNK + t * 4;
    int c[4]; int tsum = 0;
#pragma unroll
    for (int i = 0; i < 4; ++i) { int idx = base + i; c[i] = (idx < NN) ? counts[idx] : 0; tsum += c[i]; }
    sh[t] = tsum; __syncthreads();
    for (int off = 1; off < 256; off <<= 1) {
        int add = (t >= off) ? sh[t - off] : 0;
        __syncthreads();
        sh[t] += add;
        __syncthreads();
    }
    int excl = sh[t] - tsum + bsum[b];
#pragma unroll
    for (int i = 0; i < 4; ++i) {
        int idx = base + i;
        if (idx < NN) offs[idx] = excl;
        excl += c[i];
    }
}

// ---- CSR fill: (src, val) pairs bucketed by dst
__global__ void fill_kernel(const int* __restrict__ src, const int* __restrict__ dst,
                            const float* __restrict__ vals, const int* __restrict__ offs,
                            int* __restrict__ cursor, int2* __restrict__ pair) {
    int e = blockIdx.x * blockDim.x + threadIdx.x;
    if (e >= NE) return;
    int d = dst[e];
    int pos = offs[d] + atomicAdd(&cursor[d], 1);
    pair[pos] = make_int2(src[e], __float_as_int(vals[e]));
}

// ---- gather SpMM: one wave per node; 4 edges per iteration, float4 per lane.
// lane = sub(2b: edge slot) x dq(4b: dim-quad). One iteration gathers
// 4 rows x 256B = 1024B in one coalesced instruction. Shuffle-reduce at end.
__global__ __launch_bounds__(256) void spmm_kernel(
        const int* __restrict__ offs, const int2* __restrict__ pair,
        const float* __restrict__ ego, float* __restrict__ side) {
    int gid = blockIdx.x * blockDim.x + threadIdx.x;
    int node = gid >> 6;
    if (node >= NN) return;
    int lane = threadIdx.x & 63;
    int sub = lane >> 4;       // which of the 4 edges
    int dq  = lane & 15;       // which dim-quad of the row
    int beg = offs[node], end = offs[node + 1];
    float4 acc = make_float4(0.f, 0.f, 0.f, 0.f);
    int i = beg;
    for (; i + 4 <= end; i += 4) {
        int2 p = pair[i + sub];
        float w = __int_as_float(p.y);
        float4 v = ((const float4*)(ego + (size_t)p.x * DD))[dq];
        acc.x = fmaf(w, v.x, acc.x);
        acc.y = fmaf(w, v.y, acc.y);
        acc.z = fmaf(w, v.z, acc.z);
        acc.w = fmaf(w, v.w, acc.w);
    }
    if (i < end) {
        int r = end - i;
        if (sub < r) {
            int2 p = pair[i + sub];
            float w = __int_as_float(p.y);
            float4 v = ((const float4*)(ego + (size_t)p.x * DD))[dq];
            acc.x = fmaf(w, v.x, acc.x);
            acc.y = fmaf(w, v.y, acc.y);
            acc.z = fmaf(w, v.z, acc.z);
            acc.w = fmaf(w, v.w, acc.w);
        }
    }
    // reduce the 4 sub-slots: lanes dq, dq+16, dq+32, dq+48
    acc.x += __shfl_xor(acc.x, 16); acc.y += __shfl_xor(acc.y, 16);
    acc.z += __shfl_xor(acc.z, 16); acc.w += __shfl_xor(acc.w, 16);
    acc.x += __shfl_xor(acc.x, 32); acc.y += __shfl_xor(acc.y, 32);
    acc.z += __shfl_xor(acc.z, 32); acc.w += __shfl_xor(acc.w, 32);
    if (sub == 0) ((float4*)(side + (size_t)node * DD))[dq] = acc;
}

// ---- fused projection + leaky_relu + sum + in-place ego update + l2norm output.
// W staged in LDS once per block (32 KB); all W reads are wave-uniform
// ds_read_b128 broadcasts (conflict-free). s/m rows live in VGPRs.
__global__ __launch_bounds__(256) void update_kernel(
        const float* __restrict__ side, float* __restrict__ ego,
        const float* __restrict__ Wg, const float* __restrict__ bg,
        const float* __restrict__ Wb, const float* __restrict__ bb,
        float* __restrict__ out, int layer) {
    __shared__ float wg_l[DD * DD];
    __shared__ float wb_l[DD * DD];
    int t = threadIdx.x;
    {
        const float4* g4 = (const float4*)Wg;
        const float4* b4 = (const float4*)Wb;
        float4* lg = (float4*)wg_l;
        float4* lb = (float4*)wb_l;
#pragma unroll
        for (int i = 0; i < 4; ++i) {
            lg[t + 256 * i] = g4[t + 256 * i];
            lb[t + 256 * i] = b4[t + 256 * i];
        }
    }
    __syncthreads();
    int n = blockIdx.x * blockDim.x + t;
    if (n >= NN) return;   // no further __syncthreads below

    float s[DD], m[DD];
    const float4* sp = (const float4*)(side + (size_t)n * DD);
    const float4* ep = (const float4*)(ego + (size_t)n * DD);
#pragma unroll
    for (int k = 0; k < DD / 4; ++k) {
        float4 sv = sp[k], ev = ep[k];
        s[4 * k + 0] = sv.x; s[4 * k + 1] = sv.y; s[4 * k + 2] = sv.z; s[4 * k + 3] = sv.w;
        m[4 * k + 0] = sv.x * ev.x; m[4 * k + 1] = sv.y * ev.y;
        m[4 * k + 2] = sv.z * ev.z; m[4 * k + 3] = sv.w * ev.w;
    }

    float* erow = ego + (size_t)n * DD;
    float nrm = 0.f;
    for (int jq = 0; jq < 16; ++jq) {          // rolled: W addrs wave-uniform
        int j0 = jq * 4;
        float ag[4], ab[4];
#pragma unroll
        for (int i = 0; i < 4; ++i) { ag[i] = bg[j0 + i]; ab[i] = bb[j0 + i]; }
#pragma unroll
        for (int k4 = 0; k4 < 16; ++k4) {
            float4 wg[4], wb[4];
#pragma unroll
            for (int i = 0; i < 4; ++i) {
                wg[i] = *(const float4*)(wg_l + (j0 + i) * DD + k4 * 4);
                wb[i] = *(const float4*)(wb_l + (j0 + i) * DD + k4 * 4);
            }
#pragma unroll
            for (int i = 0; i < 4; ++i) {
                int k = k4 * 4;
                ag[i] = fmaf(s[k + 0], wg[i].x, ag[i]);
                ag[i] = fmaf(s[k + 1], wg[i].y, ag[i]);
                ag[i] = fmaf(s[k + 2], wg[i].z, ag[i]);
                ag[i] = fmaf(s[k + 3], wg[i].w, ag[i]);
                ab[i] = fmaf(m[k + 0], wb[i].x, ab[i]);
                ab[i] = fmaf(m[k + 1], wb[i].y, ab[i]);
                ab[i] = fmaf(m[k + 2], wb[i].z, ab[i]);
                ab[i] = fmaf(m[k + 3], wb[i].w, ab[i]);
            }
        }
        float vv[4];
#pragma unroll
        for (int i = 0; i < 4; ++i) {
            float g = (ag[i] > 0.f) ? ag[i] : 0.01f * ag[i];
            float b = (ab[i] > 0.f) ? ab[i] : 0.01f * ab[i];
            float v = g + b;
            vv[i] = v;
            nrm = fmaf(v, v, nrm);
        }
        ((float4*)erow)[jq] = make_float4(vv[0], vv[1], vv[2], vv[3]);
    }
    float rinv = 1.f / fmaxf(sqrtf(nrm), 1e-12f);
    float4* orow = (float4*)(out + (size_t)n * (DD * (NL + 1)) + (layer + 1) * DD);
    const float4* er4 = (const float4*)erow;   // re-read own row (L1-hot)
#pragma unroll
    for (int k = 0; k < DD / 4; ++k) {
        float4 v = er4[k];
        orow[k] = make_float4(v.x * rinv, v.y * rinv, v.z * rinv, v.w * rinv);
    }
}

extern "C" void kernel_launch(void* const* d_in, const int* in_sizes, int n_in,
                              void* d_out, int out_size, void* d_ws, size_t ws_size,
                              hipStream_t stream) {
    const int*   edge_src  = (const int*)d_in[0];
    const int*   edge_dst  = (const int*)d_in[1];
    const float* edge_vals = (const float*)d_in[2];
    const float* uemb      = (const float*)d_in[3];
    const float* iemb      = (const float*)d_in[4];
    const float* Wgc       = (const float*)d_in[5];
    const float* bgc       = (const float*)d_in[6];
    const float* Wbi       = (const float*)d_in[7];
    const float* bbi       = (const float*)d_in[8];
    float* out = (float*)d_out;

    char* p = (char*)d_ws;
    auto alloc = [&](size_t bytes) { char* r = p; p += (bytes + 255) & ~(size_t)255; return r; };
    int*   counts = (int*)alloc((size_t)NN * 4);
    int*   offs   = (int*)alloc((size_t)(NN + 1) * 4);
    int*   bsum   = (int*)alloc((size_t)NB * 4);
    int2*  pair   = (int2*)alloc((size_t)NE * 8);
    float* ego    = (float*)alloc((size_t)NN * DD * 4);
    float* side   = (float*)alloc((size_t)NN * DD * 4);

    hipMemsetAsync(counts, 0, (size_t)NN * 4, stream);
    init_kernel<<<(NN * DD + 255) / 256, 256, 0, stream>>>(uemb, iemb, ego, out);
    hist_kernel<<<(NE + 255) / 256, 256, 0, stream>>>(edge_dst, counts);
    scanA_kernel<<<NB, 256, 0, stream>>>(counts, bsum);
    scanB_kernel<<<1, 256, 0, stream>>>(bsum, offs);
    scanC_kernel<<<NB, 256, 0, stream>>>(counts, bsum, offs);
    hipMemsetAsync(counts, 0, (size_t)NN * 4, stream);
    fill_kernel<<<(NE + 255) / 256, 256, 0, stream>>>(edge_src, edge_dst, edge_vals, offs, counts, pair);

    for (int l = 0; l < NL; ++l) {
        spmm_kernel<<<(NN * 64 + 255) / 256, 256, 0, stream>>>(offs, pair, ego, side);
        update_kernel<<<(NN + 255) / 256, 256, 0, stream>>>(
            side, ego, Wgc + l * DD * DD, bgc + l * DD, Wbi + l * DD * DD, bbi + l * DD,
            out, l);
    }
}

// Round 3
// 1318.583 us; speedup vs baseline: 1.5459x; 1.1419x over previous
//
#include <hip/hip_runtime.h>

#define NU 50000
#define NI 100000
#define NN 150000
#define NE 2400000
#define DD 64
#define NL 3
#define CHUNK 1024
#define NB ((NN + CHUNK - 1) / CHUNK)   // 147 scan blocks

// ---- init: ego = concat(user_emb, item_emb); out[:, 0:64] = ego (layer-0, un-normalized)
__global__ void init_kernel(const float* __restrict__ uemb, const float* __restrict__ iemb,
                            float* __restrict__ ego, float* __restrict__ out) {
    int i = blockIdx.x * blockDim.x + threadIdx.x;
    if (i >= NN * DD) return;
    int n = i >> 6, d = i & 63;
    float v = (n < NU) ? uemb[i] : iemb[i - NU * DD];
    ego[i] = v;
    out[n * (DD * (NL + 1)) + d] = v;
}

// ---- CSR build: histogram of dst
__global__ void hist_kernel(const int* __restrict__ dst, int* __restrict__ counts) {
    int e = blockIdx.x * blockDim.x + threadIdx.x;
    if (e < NE) atomicAdd(&counts[dst[e]], 1);
}

// ---- scan stage A: per-block (1024-elem chunk) totals
__global__ void scanA_kernel(const int* __restrict__ counts, int* __restrict__ bsum) {
    __shared__ int sh[256];
    int t = threadIdx.x, b = blockIdx.x;
    int base = b * CHUNK + t * 4;
    int s = 0;
#pragma unroll
    for (int i = 0; i < 4; ++i) { int idx = base + i; if (idx < NN) s += counts[idx]; }
    sh[t] = s; __syncthreads();
    for (int off = 128; off > 0; off >>= 1) {
        if (t < off) sh[t] += sh[t + off];
        __syncthreads();
    }
    if (t == 0) bsum[b] = sh[0];
}

// ---- scan stage B: exclusive scan of the NB(=147) block sums, one block
__global__ void scanB_kernel(int* __restrict__ bsum, int* __restrict__ offs) {
    __shared__ int sh[256];
    int t = threadIdx.x;
    int v = (t < NB) ? bsum[t] : 0;
    sh[t] = v; __syncthreads();
    for (int off = 1; off < 256; off <<= 1) {
        int add = (t >= off) ? sh[t - off] : 0;
        __syncthreads();
        sh[t] += add;
        __syncthreads();
    }
    if (t < NB) bsum[t] = sh[t] - v;          // exclusive block offset
    if (t == NB - 1) offs[NN] = sh[t];        // total == NE
}

// ---- scan stage C: full exclusive scan -> offs
__global__ void scanC_kernel(const int* __restrict__ counts, const int* __restrict__ bsum,
                             int* __restrict__ offs) {
    __shared__ int sh[256];
    int t = threadIdx.x, b = blockIdx.x;
    int base = b * CHUNK + t * 4;
    int c[4]; int tsum = 0;
#pragma unroll
    for (int i = 0; i < 4; ++i) { int idx = base + i; c[i] = (idx < NN) ? counts[idx] : 0; tsum += c[i]; }
    sh[t] = tsum; __syncthreads();
    for (int off = 1; off < 256; off <<= 1) {
        int add = (t >= off) ? sh[t - off] : 0;
        __syncthreads();
        sh[t] += add;
        __syncthreads();
    }
    int excl = sh[t] - tsum + bsum[b];
#pragma unroll
    for (int i = 0; i < 4; ++i) {
        int idx = base + i;
        if (idx < NN) offs[idx] = excl;
        excl += c[i];
    }
}

// ---- CSR fill: (src, val) pairs bucketed by dst
__global__ void fill_kernel(const int* __restrict__ src, const int* __restrict__ dst,
                            const float* __restrict__ vals, const int* __restrict__ offs,
                            int* __restrict__ cursor, int2* __restrict__ pair) {
    int e = blockIdx.x * blockDim.x + threadIdx.x;
    if (e >= NE) return;
    int d = dst[e];
    int pos = offs[d] + atomicAdd(&cursor[d], 1);
    pair[pos] = make_int2(src[e], __float_as_int(vals[e]));
}

// ---- gather SpMM: one wave per node; 4 edges per iteration, float4 per lane.
__global__ __launch_bounds__(256) void spmm_kernel(
        const int* __restrict__ offs, const int2* __restrict__ pair,
        const float* __restrict__ ego, float* __restrict__ side) {
    int gid = blockIdx.x * blockDim.x + threadIdx.x;
    int node = gid >> 6;
    if (node >= NN) return;
    int lane = threadIdx.x & 63;
    int sub = lane >> 4;       // which of the 4 edges
    int dq  = lane & 15;       // which dim-quad of the row
    int beg = offs[node], end = offs[node + 1];
    float4 acc = make_float4(0.f, 0.f, 0.f, 0.f);
    int i = beg;
    for (; i + 4 <= end; i += 4) {
        int2 p = pair[i + sub];
        float w = __int_as_float(p.y);
        float4 v = ((const float4*)(ego + (size_t)p.x * DD))[dq];
        acc.x = fmaf(w, v.x, acc.x);
        acc.y = fmaf(w, v.y, acc.y);
        acc.z = fmaf(w, v.z, acc.z);
        acc.w = fmaf(w, v.w, acc.w);
    }
    if (i < end) {
        int r = end - i;
        if (sub < r) {
            int2 p = pair[i + sub];
            float w = __int_as_float(p.y);
            float4 v = ((const float4*)(ego + (size_t)p.x * DD))[dq];
            acc.x = fmaf(w, v.x, acc.x);
            acc.y = fmaf(w, v.y, acc.y);
            acc.z = fmaf(w, v.z, acc.z);
            acc.w = fmaf(w, v.w, acc.w);
        }
    }
    acc.x += __shfl_xor(acc.x, 16); acc.y += __shfl_xor(acc.y, 16);
    acc.z += __shfl_xor(acc.z, 16); acc.w += __shfl_xor(acc.w, 16);
    acc.x += __shfl_xor(acc.x, 32); acc.y += __shfl_xor(acc.y, 32);
    acc.z += __shfl_xor(acc.z, 32); acc.w += __shfl_xor(acc.w, 32);
    if (sub == 0) ((float4*)(side + (size_t)node * DD))[dq] = acc;
}

// ---- update: W in per-lane VGPRs (lane j holds row j of Wg and Wb).
// Each wave streams a strip of nodes; side/ego rows are read at wave-uniform
// addresses (node made uniform via readfirstlane) -> scalar s_load path, so
// the inner loop is v_fma(sgpr, vgpr, vgpr). No LDS. Norm via shfl reduce.
#define UPD_WAVES_PER_BLOCK 4
#define UPD_BLOCKS 1024
#define UPD_NPW 40   // nodes per wave: 1024*4*40 = 163840 >= NN
__global__ __launch_bounds__(256) void update_kernel(
        const float* __restrict__ side, float* __restrict__ ego,
        const float* __restrict__ Wg, const float* __restrict__ bg,
        const float* __restrict__ Wb, const float* __restrict__ bb,
        float* __restrict__ out, int layer) {
    int lane = threadIdx.x & 63;
    int wid = __builtin_amdgcn_readfirstlane(threadIdx.x >> 6);   // uniform
    int gwave = blockIdx.x * UPD_WAVES_PER_BLOCK + wid;           // uniform
    int n_beg = gwave * UPD_NPW;
    int n_end = n_beg + UPD_NPW;
    if (n_end > NN) n_end = NN;
    if (n_beg >= n_end) return;

    // lane j's W rows -> 128 VGPRs
    float wg[DD], wb[DD];
    {
        const float4* g4 = (const float4*)(Wg + lane * DD);
        const float4* b4 = (const float4*)(Wb + lane * DD);
#pragma unroll
        for (int k4 = 0; k4 < 16; ++k4) {
            float4 a = g4[k4];
            wg[4 * k4 + 0] = a.x; wg[4 * k4 + 1] = a.y; wg[4 * k4 + 2] = a.z; wg[4 * k4 + 3] = a.w;
            float4 b = b4[k4];
            wb[4 * k4 + 0] = b.x; wb[4 * k4 + 1] = b.y; wb[4 * k4 + 2] = b.z; wb[4 * k4 + 3] = b.w;
        }
    }
    float bgj = bg[lane], bbj = bb[lane];

    for (int n2 = n_beg; n2 < n_end; n2 += 2) {
        float v[2], sq[2];
#pragma unroll
        for (int u = 0; u < 2; ++u) {
            int n = n2 + u;
            if (n < n_end) {
                const float* sr = side + (size_t)n * DD;   // uniform addr -> s_load
                const float* er = ego + (size_t)n * DD;    // uniform addr -> s_load
                float ag = bgj, ab = bbj;
#pragma unroll
                for (int k = 0; k < DD; ++k) {
                    float sk = sr[k];
                    float mk = sk * er[k];
                    ag = fmaf(sk, wg[k], ag);
                    ab = fmaf(mk, wb[k], ab);
                }
                ag = (ag > 0.f) ? ag : 0.01f * ag;
                ab = (ab > 0.f) ? ab : 0.01f * ab;
                v[u] = ag + ab;
                sq[u] = v[u] * v[u];
            } else { v[u] = 0.f; sq[u] = 0.f; }
        }
        // two independent 64-lane reductions (interleaved for ILP)
#pragma unroll
        for (int off = 1; off < 64; off <<= 1) {
            sq[0] += __shfl_xor(sq[0], off);
            sq[1] += __shfl_xor(sq[1], off);
        }
#pragma unroll
        for (int u = 0; u < 2; ++u) {
            int n = n2 + u;
            if (n < n_end) {
                float rinv = 1.f / fmaxf(sqrtf(sq[u]), 1e-12f);
                ego[(size_t)n * DD + lane] = v[u];
                out[(size_t)n * (DD * (NL + 1)) + (layer + 1) * DD + lane] = v[u] * rinv;
            }
        }
    }
}

extern "C" void kernel_launch(void* const* d_in, const int* in_sizes, int n_in,
                              void* d_out, int out_size, void* d_ws, size_t ws_size,
                              hipStream_t stream) {
    const int*   edge_src  = (const int*)d_in[0];
    const int*   edge_dst  = (const int*)d_in[1];
    const float* edge_vals = (const float*)d_in[2];
    const float* uemb      = (const float*)d_in[3];
    const float* iemb      = (const float*)d_in[4];
    const float* Wgc       = (const float*)d_in[5];
    const float* bgc       = (const float*)d_in[6];
    const float* Wbi       = (const float*)d_in[7];
    const float* bbi       = (const float*)d_in[8];
    float* out = (float*)d_out;

    char* p = (char*)d_ws;
    auto alloc = [&](size_t bytes) { char* r = p; p += (bytes + 255) & ~(size_t)255; return r; };
    int*   counts = (int*)alloc((size_t)NN * 4);
    int*   offs   = (int*)alloc((size_t)(NN + 1) * 4);
    int*   bsum   = (int*)alloc((size_t)NB * 4);
    int2*  pair   = (int2*)alloc((size_t)NE * 8);
    float* ego    = (float*)alloc((size_t)NN * DD * 4);
    float* side   = (float*)alloc((size_t)NN * DD * 4);

    hipMemsetAsync(counts, 0, (size_t)NN * 4, stream);
    init_kernel<<<(NN * DD + 255) / 256, 256, 0, stream>>>(uemb, iemb, ego, out);
    hist_kernel<<<(NE + 255) / 256, 256, 0, stream>>>(edge_dst, counts);
    scanA_kernel<<<NB, 256, 0, stream>>>(counts, bsum);
    scanB_kernel<<<1, 256, 0, stream>>>(bsum, offs);
    scanC_kernel<<<NB, 256, 0, stream>>>(counts, bsum, offs);
    hipMemsetAsync(counts, 0, (size_t)NN * 4, stream);
    fill_kernel<<<(NE + 255) / 256, 256, 0, stream>>>(edge_src, edge_dst, edge_vals, offs, counts, pair);

    for (int l = 0; l < NL; ++l) {
        spmm_kernel<<<(NN * 64 + 255) / 256, 256, 0, stream>>>(offs, pair, ego, side);
        update_kernel<<<UPD_BLOCKS, 256, 0, stream>>>(
            side, ego, Wgc + l * DD * DD, bgc + l * DD, Wbi + l * DD * DD, bbi + l * DD,
            out, l);
    }
}